// Round 5
// baseline (1382.744 us; speedup 1.0000x reference)
//
#include <hip/hip_runtime.h>

#define T_STEPS 512
#define BATCH   512
#define HID     64
#define CH      8     // steps per chunk; xg + hstash fully register-resident

#define PIN(x) asm volatile("" : "+v"(x))

// SGPR broadcast: value of v in lane k, as a wave-uniform scalar operand.
__device__ __forceinline__ float rlane(float v, int k) {
    return __uint_as_float(__builtin_amdgcn_readlane(__float_as_uint(v), k));
}
__device__ __forceinline__ float rcpf(float x) { return __builtin_amdgcn_rcpf(x); }
__device__ __forceinline__ float fast_tanh(float x) {
    // tanh(x) = 1 - 2/(1+e^{2x}); saturates correctly, no NaN.
    return 1.0f - 2.0f * rcpf(1.0f + __expf(2.0f * x));
}

// One block per batch row, 256 threads, 2 blocks/CU.
// Mapping: wave w, lane l; gid = l>>4 (gate i,f,g,o), u = w*16+(l&15) (unit),
// gate row gr = gid*64+u. The 4 gates of unit u are in ONE wave at lanes
// l^16/l^32/l^48 -> 3 intra-wave shuffles; one barrier per step; hbuf parity-
// double-buffered. All shared-vector dots use per-lane VGPR + readlane
// (SGPR broadcast) instead of per-thread LDS broadcast reads.
template<int K_IN, bool LAST>
__global__ __launch_bounds__(256, 2)
void lstm_layer(const float* __restrict__ xin,   // [B,T,K_IN]
                const float* __restrict__ W_ih,  // [256,K_IN]
                const float* __restrict__ W_hh,  // [256,64]
                const float* __restrict__ b_ih,  // [256]
                const float* __restrict__ b_hh,  // [256]
                float* __restrict__ hout,        // [B,T,64] (if !LAST)
                const float* __restrict__ W_fc,  // [1,64]   (if LAST)
                const float* __restrict__ b_fc,  // [1]      (if LAST)
                float* __restrict__ fcout)       // [B]      (if LAST)
{
    __shared__ float hbuf[2][HID];   // only LDS in the kernel (512 B)

    const int b   = blockIdx.x;
    const int tid = threadIdx.x;
    const int w   = tid >> 6;
    const int l   = tid & 63;
    const int gid = l >> 4;               // 0=i 1=f 2=g 3=o
    const int u   = (w << 4) + (l & 15);  // hidden unit
    const int gr  = (gid << 6) + u;       // gate row

    // Branchless activation: act(x) = sB + sC * rcp(1+exp(sA*x)).
    const bool istanh = (gid == 2);
    const float sA = istanh ? 2.0f : -1.0f;
    const float sB = istanh ? 1.0f : 0.0f;
    const float sC = istanh ? -2.0f : 1.0f;

    // Persistent weight rows (this thread's gate row).
    float whh[HID];
    {
        const float4* hr = reinterpret_cast<const float4*>(W_hh + (size_t)gr * HID);
        #pragma unroll
        for (int k = 0; k < HID / 4; ++k) {
            float4 v = hr[k];
            whh[4*k+0] = v.x; whh[4*k+1] = v.y; whh[4*k+2] = v.z; whh[4*k+3] = v.w;
        }
        #pragma unroll
        for (int k = 0; k < HID; ++k) PIN(whh[k]);
    }
    float wih[K_IN];
    {
        const float4* xr = reinterpret_cast<const float4*>(W_ih + (size_t)gr * K_IN);
        #pragma unroll
        for (int k = 0; k < K_IN / 4; ++k) {
            float4 v = xr[k];
            wih[4*k+0] = v.x; wih[4*k+1] = v.y; wih[4*k+2] = v.z; wih[4*k+3] = v.w;
        }
        #pragma unroll
        for (int k = 0; k < K_IN; ++k) PIN(wih[k]);
    }
    const float bias = b_ih[gr] + b_hh[gr];

    if (tid < 128) hbuf[tid >> 6][tid & 63] = 0.0f;
    float c = 0.0f;
    __syncthreads();

    const float* xrow = xin + (size_t)b * T_STEPS * K_IN;
    float hstash[CH];   // dead when LAST

    for (int c0 = 0; c0 < T_STEPS; c0 += CH) {
        // ---- xg for this chunk, fully in registers ----
        // x loaded per-lane from global (coalesced 256B/wave, L1-served for
        // the 4-wave redundancy), broadcast via readlane.
        float xg[CH];
        if (K_IN == 32) {
            #pragma unroll
            for (int tm = 0; tm < CH; tm += 2) {
                // lanes 0..31 -> x[tm][l], lanes 32..63 -> x[tm+1][l-32]
                const float v = xrow[(c0 + tm) * 32 + l];
                float a0 = bias, a1 = 0.f, a2 = 0.f, a3 = 0.f;
                float b0 = bias, b1 = 0.f, b2 = 0.f, b3 = 0.f;
                #pragma unroll
                for (int k = 0; k < 32; k += 4) {
                    a0 = fmaf(wih[k+0], rlane(v, k+0), a0);
                    a1 = fmaf(wih[k+1], rlane(v, k+1), a1);
                    a2 = fmaf(wih[k+2], rlane(v, k+2), a2);
                    a3 = fmaf(wih[k+3], rlane(v, k+3), a3);
                    b0 = fmaf(wih[k+0], rlane(v, 32+k+0), b0);
                    b1 = fmaf(wih[k+1], rlane(v, 32+k+1), b1);
                    b2 = fmaf(wih[k+2], rlane(v, 32+k+2), b2);
                    b3 = fmaf(wih[k+3], rlane(v, 32+k+3), b3);
                }
                xg[tm]     = (a0 + a1) + (a2 + a3);
                xg[tm + 1] = (b0 + b1) + (b2 + b3);
            }
        } else {
            #pragma unroll
            for (int tm = 0; tm < CH; ++tm) {
                const float v = xrow[(c0 + tm) * 64 + l];
                float a0 = bias, a1 = 0.f, a2 = 0.f, a3 = 0.f;
                #pragma unroll
                for (int k = 0; k < 64; k += 4) {
                    a0 = fmaf(wih[k+0], rlane(v, k+0), a0);
                    a1 = fmaf(wih[k+1], rlane(v, k+1), a1);
                    a2 = fmaf(wih[k+2], rlane(v, k+2), a2);
                    a3 = fmaf(wih[k+3], rlane(v, k+3), a3);
                }
                xg[tm] = (a0 + a1) + (a2 + a3);
            }
        }

        // ---- Serial recurrence: 1 ds_read_b32 + 64 readlane + 64 FMA ----
        #pragma unroll
        for (int tm = 0; tm < CH; ++tm) {
            const int p = (c0 + tm) & 1;
            const float hv = hbuf[p][l];   // per-lane distinct, conflict-free
            float a0 = xg[tm], a1 = 0.f, a2 = 0.f, a3 = 0.f;
            #pragma unroll
            for (int k = 0; k < HID; k += 4) {
                a0 = fmaf(whh[k+0], rlane(hv, k+0), a0);
                a1 = fmaf(whh[k+1], rlane(hv, k+1), a1);
                a2 = fmaf(whh[k+2], rlane(hv, k+2), a2);
                a3 = fmaf(whh[k+3], rlane(hv, k+3), a3);
            }
            const float acc = (a0 + a1) + (a2 + a3);
            const float act = sB + sC * rcpf(1.0f + __expf(sA * acc));

            // Gather the 4 gates of unit u into the gid==0 lane (intra-wave).
            const float s1 = __shfl_xor(act, 16);   // gid^1
            const float s2 = __shfl_xor(act, 32);   // gid^2
            const float s3 = __shfl_xor(s1, 32);    // gid^3
            if (gid == 0) {
                // act=i, s1=f, s2=g, s3=o
                c = fmaf(s1, c, act * s2);
                const float h = s3 * fast_tanh(c);
                hbuf[p ^ 1][u] = h;
                if (!LAST) hstash[tm] = h;   // store batched after the chunk
            }
            __syncthreads();   // h(t) visible for next step
        }

        // Batched h1 stores: off the per-step barrier/vmcnt path.
        if (!LAST && gid == 0) {
            #pragma unroll
            for (int tm = 0; tm < CH; ++tm)
                hout[((size_t)b * T_STEPS + (c0 + tm)) * HID + u] = hstash[tm];
        }
    }

    if (LAST) {
        // t=511 wrote parity (511&1)^1 = 0.
        if (tid < HID) {
            float v = hbuf[0][tid] * W_fc[tid];
            #pragma unroll
            for (int off = 32; off; off >>= 1) v += __shfl_down(v, off);
            if (tid == 0) fcout[b] = v + b_fc[0];
        }
    }
}

extern "C" void kernel_launch(void* const* d_in, const int* in_sizes, int n_in,
                              void* d_out, int out_size, void* d_ws, size_t ws_size,
                              hipStream_t stream) {
    const float* x     = (const float*)d_in[0];
    const float* W_ih0 = (const float*)d_in[1];
    const float* W_hh0 = (const float*)d_in[2];
    const float* b_ih0 = (const float*)d_in[3];
    const float* b_hh0 = (const float*)d_in[4];
    const float* W_ih1 = (const float*)d_in[5];
    const float* W_hh1 = (const float*)d_in[6];
    const float* b_ih1 = (const float*)d_in[7];
    const float* b_hh1 = (const float*)d_in[8];
    const float* W_fc  = (const float*)d_in[9];
    const float* b_fc  = (const float*)d_in[10];

    float* out = (float*)d_out;
    float* h1  = (float*)d_ws;   // [512,512,64] f32 = 64 MB scratch

    lstm_layer<32, false><<<BATCH, 256, 0, stream>>>(
        x, W_ih0, W_hh0, b_ih0, b_hh0, h1, nullptr, nullptr, nullptr);
    lstm_layer<64, true><<<BATCH, 256, 0, stream>>>(
        h1, W_ih1, W_hh1, b_ih1, b_hh1, nullptr, W_fc, b_fc, out);
}

// Round 6
// 1060.229 us; speedup vs baseline: 1.3042x; 1.3042x over previous
//
#include <hip/hip_runtime.h>

#define T_STEPS 512
#define HID     64
#define NB      16    // batch rows per block
#define CH      4     // steps per xg chunk (register-resident)

typedef __attribute__((ext_vector_type(8))) short bf16x8;   // 8 bf16 = 4 VGPR
typedef __attribute__((ext_vector_type(4))) short short4v;  // 8B
typedef __attribute__((ext_vector_type(4))) float f32x4;

#define MFMA __builtin_amdgcn_mfma_f32_16x16x32_bf16

__device__ __forceinline__ unsigned short f2bf(float f) {   // RNE f32->bf16
    unsigned u = __float_as_uint(f);
    return (unsigned short)((u + 0x7fffu + ((u >> 16) & 1u)) >> 16);
}
__device__ __forceinline__ float bf2f(unsigned short h) {
    return __uint_as_float(((unsigned)h) << 16);
}
// Split 8 f32 into bf16 hi + bf16 lo(residual): hi+lo carries ~16-bit mantissa.
__device__ __forceinline__ void split8(float4 a, float4 b, bf16x8& hi, bf16x8& lo) {
    float v[8] = {a.x, a.y, a.z, a.w, b.x, b.y, b.z, b.w};
    #pragma unroll
    for (int j = 0; j < 8; ++j) {
        unsigned short h = f2bf(v[j]);
        hi[j] = (short)h;
        lo[j] = (short)f2bf(v[j] - bf2f(h));
    }
}
__device__ __forceinline__ float sigm(float x) {
    return __builtin_amdgcn_rcpf(1.0f + __expf(-x));
}
__device__ __forceinline__ float tanh_(float x) {
    return 1.0f - 2.0f * __builtin_amdgcn_rcpf(1.0f + __expf(2.0f * x));
}

// One block = NB(16) batch rows, 256 threads (4 waves), grid = B/NB = 32.
// Wave w owns gate-tiles m = w+4*ti (ti: 0=i,1=f,2=g,3=o). MFMA frag roles per
// lane l: A row = l&15, A/B k = (l>>4)*8+j (consistent A/B k-map => correct);
// C/D: col = l&15 (batch), row = (l>>4)*4+reg (unit offset in tile) [m89].
// => thread holds i,f,g,o of units u0..u0+3 for one batch col: c/h update is
// thread-local. h redistributed via small LDS (bf16 hi/lo, parity dbuf),
// 1 barrier/step. xg (x-part of gates) MFMA'd per CH-chunk into registers,
// x prefetched one chunk ahead.
template<int K_IN, bool LAST>
__global__ __launch_bounds__(256, 1)
void lstm_mfma(const float* __restrict__ xin,   // [B,T,K_IN]
               const float* __restrict__ W_ih,  // [256,K_IN]
               const float* __restrict__ W_hh,  // [256,64]
               const float* __restrict__ b_ih,  // [256]
               const float* __restrict__ b_hh,  // [256]
               float* __restrict__ hout,        // [B,T,64]  (!LAST)
               const float* __restrict__ W_fc,  // [1,64]    (LAST)
               const float* __restrict__ b_fc,  // [1]       (LAST)
               float* __restrict__ fcout)       // [B]       (LAST)
{
    constexpr int KS = K_IN / 32;               // k-slices for the x-path
    __shared__ __align__(16) unsigned short HsHi[2][NB * 72];  // stride 72: bank-spread
    __shared__ __align__(16) unsigned short HsLo[2][NB * 72];
    __shared__ float Ys[4][NB];

    const int tid = threadIdx.x;
    const int w   = tid >> 6, l = tid & 63;
    const int c   = l & 15;          // batch col (also A-row index, same value)
    const int g4  = l >> 4;          // lane group
    const int b0  = blockIdx.x * NB;
    const int u0  = 16 * w + 4 * g4; // first unit of this thread's C rows

    // ---- Load + split weights into MFMA A-fragments (static, small) ----
    bf16x8 whhH[4][2], whhL[4][2];
    bf16x8 wihH[4][KS], wihL[4][KS];
    f32x4  bias4[4];
    #pragma unroll
    for (int ti = 0; ti < 4; ++ti) {
        const int m = w + 4 * ti;
        const int arow = 16 * m + (l & 15);
        #pragma unroll
        for (int ks = 0; ks < 2; ++ks) {
            const float* p = W_hh + (size_t)arow * HID + ks * 32 + 8 * g4;
            split8(*(const float4*)p, *(const float4*)(p + 4), whhH[ti][ks], whhL[ti][ks]);
        }
        #pragma unroll
        for (int ks = 0; ks < KS; ++ks) {
            const float* p = W_ih + (size_t)arow * K_IN + ks * 32 + 8 * g4;
            split8(*(const float4*)p, *(const float4*)(p + 4), wihH[ti][ks], wihL[ti][ks]);
        }
        const int br = 16 * m + 4 * g4;          // C-row gate index base
        float4 bi = *(const float4*)(b_ih + br);
        float4 bh = *(const float4*)(b_hh + br);
        bias4[ti] = (f32x4){bi.x + bh.x, bi.y + bh.y, bi.z + bh.z, bi.w + bh.w};
    }

    // ---- Zero h state (parity 0) ----
    #pragma unroll
    for (int r = 0; r < 4; ++r) {
        HsHi[0][c * 72 + u0 + r] = 0;
        HsLo[0][c * 72 + u0 + r] = 0;
    }
    float cst[4] = {0.f, 0.f, 0.f, 0.f};
    float part = 0.0f;

    // ---- Prefetch x chunk 0 (per-lane: 8 consecutive k for (col,t)) ----
    const float* xbase = xin + (size_t)(b0 + c) * T_STEPS * K_IN + 8 * g4;
    float4 xraw[CH][KS][2];
    #pragma unroll
    for (int tt = 0; tt < CH; ++tt)
        #pragma unroll
        for (int ks = 0; ks < KS; ++ks) {
            const float* p = xbase + (size_t)tt * K_IN + ks * 32;
            xraw[tt][ks][0] = *(const float4*)p;
            xraw[tt][ks][1] = *(const float4*)(p + 4);
        }
    __syncthreads();

    for (int c0 = 0; c0 < T_STEPS; c0 += CH) {
        // ---- Burst: xg for this chunk (registers only) ----
        f32x4 xga[CH][4];
        #pragma unroll
        for (int tt = 0; tt < CH; ++tt) {
            bf16x8 xbH[KS], xbL[KS];
            #pragma unroll
            for (int ks = 0; ks < KS; ++ks)
                split8(xraw[tt][ks][0], xraw[tt][ks][1], xbH[ks], xbL[ks]);
            #pragma unroll
            for (int ti = 0; ti < 4; ++ti) {
                f32x4 a = bias4[ti];
                #pragma unroll
                for (int ks = 0; ks < KS; ++ks) {
                    a = MFMA(wihH[ti][ks], xbH[ks], a, 0, 0, 0);
                    a = MFMA(wihH[ti][ks], xbL[ks], a, 0, 0, 0);
                    a = MFMA(wihL[ti][ks], xbH[ks], a, 0, 0, 0);
                }
                xga[tt][ti] = a;
            }
        }
        // ---- Prefetch next chunk (latency hidden under CH serial steps) ----
        if (c0 + CH < T_STEPS) {
            #pragma unroll
            for (int tt = 0; tt < CH; ++tt)
                #pragma unroll
                for (int ks = 0; ks < KS; ++ks) {
                    const float* p = xbase + (size_t)(c0 + CH + tt) * K_IN + ks * 32;
                    xraw[tt][ks][0] = *(const float4*)p;
                    xraw[tt][ks][1] = *(const float4*)(p + 4);
                }
        }
        // ---- Serial steps ----
        #pragma unroll
        for (int tt = 0; tt < CH; ++tt) {
            const int t = c0 + tt;
            const int p = t & 1;
            __syncthreads();   // h(t-1) writes visible; guards WAR on Hs[p^1]
            bf16x8 hbH[2], hbL[2];
            #pragma unroll
            for (int ks = 0; ks < 2; ++ks) {   // B-frag: k = ks*32+8*g4+j, col c
                hbH[ks] = *(const bf16x8*)&HsHi[p][c * 72 + ks * 32 + 8 * g4];
                hbL[ks] = *(const bf16x8*)&HsLo[p][c * 72 + ks * 32 + 8 * g4];
            }
            f32x4 acc[4];
            #pragma unroll
            for (int ti = 0; ti < 4; ++ti) {
                f32x4 a = xga[tt][ti];
                #pragma unroll
                for (int ks = 0; ks < 2; ++ks) {
                    a = MFMA(whhH[ti][ks], hbH[ks], a, 0, 0, 0);
                    a = MFMA(whhH[ti][ks], hbL[ks], a, 0, 0, 0);
                    a = MFMA(whhL[ti][ks], hbH[ks], a, 0, 0, 0);
                }
                acc[ti] = a;
            }
            float hf[4];
            #pragma unroll
            for (int r = 0; r < 4; ++r) {
                float i_ = sigm(acc[0][r]);
                float f_ = sigm(acc[1][r]);
                float g_ = tanh_(acc[2][r]);
                float o_ = sigm(acc[3][r]);
                cst[r] = fmaf(f_, cst[r], i_ * g_);
                hf[r]  = o_ * tanh_(cst[r]);
            }
            short4v h4h, h4l;
            #pragma unroll
            for (int r = 0; r < 4; ++r) {
                unsigned short hh = f2bf(hf[r]);
                h4h[r] = (short)hh;
                h4l[r] = (short)f2bf(hf[r] - bf2f(hh));
            }
            *(short4v*)&HsHi[p ^ 1][c * 72 + u0] = h4h;   // ds_write_b64
            *(short4v*)&HsLo[p ^ 1][c * 72 + u0] = h4l;
            if (!LAST) {
                *(float4*)&hout[((size_t)(b0 + c) * T_STEPS + t) * HID + u0] =
                    make_float4(hf[0], hf[1], hf[2], hf[3]);
            } else if (t == T_STEPS - 1) {
                const float4 wf = *(const float4*)(W_fc + u0);
                part = hf[0] * wf.x + hf[1] * wf.y + hf[2] * wf.z + hf[3] * wf.w;
            }
        }
    }

    if (LAST) {
        // Reduce FC partials: lanes sharing col c are l, l^16, l^32, l^48.
        part += __shfl_xor(part, 16);
        part += __shfl_xor(part, 32);
        if (l < NB) Ys[w][l] = part;
        __syncthreads();
        if (tid < NB)
            fcout[b0 + tid] = Ys[0][tid] + Ys[1][tid] + Ys[2][tid] + Ys[3][tid] + b_fc[0];
    }
}

extern "C" void kernel_launch(void* const* d_in, const int* in_sizes, int n_in,
                              void* d_out, int out_size, void* d_ws, size_t ws_size,
                              hipStream_t stream) {
    const float* x     = (const float*)d_in[0];
    const float* W_ih0 = (const float*)d_in[1];
    const float* W_hh0 = (const float*)d_in[2];
    const float* b_ih0 = (const float*)d_in[3];
    const float* b_hh0 = (const float*)d_in[4];
    const float* W_ih1 = (const float*)d_in[5];
    const float* W_hh1 = (const float*)d_in[6];
    const float* b_ih1 = (const float*)d_in[7];
    const float* b_hh1 = (const float*)d_in[8];
    const float* W_fc  = (const float*)d_in[9];
    const float* b_fc  = (const float*)d_in[10];

    float* out = (float*)d_out;
    float* h1  = (float*)d_ws;   // [512,512,64] f32 = 64 MB scratch

    lstm_mfma<32, false><<<dim3(512 / NB), dim3(256), 0, stream>>>(
        x, W_ih0, W_hh0, b_ih0, b_hh0, h1, nullptr, nullptr, nullptr);
    lstm_mfma<64, true><<<dim3(512 / NB), dim3(256), 0, stream>>>(
        h1, W_ih1, W_hh1, b_ih1, b_hh1, nullptr, W_fc, b_fc, out);
}